// Round 1
// baseline (86.095 us; speedup 1.0000x reference)
//
#include <hip/hip_runtime.h>
#include <math.h>

#define EMBED 128
#define VOCAB 32000
#define MEMN  50
#define BATCH 16
#define NQ    10
#define SQ    20
#define SS    40
#define BN    (BATCH*NQ)   // 160
#define NHOPS 3

__device__ __forceinline__ float posw(int j, int J, int k) {
    // 1 - (j+1)/J - (k+1)/EMBED * (1 - 2*(j+1)/J)
    float jf = (float)(j + 1) / (float)J;
    return 1.0f - jf - ((float)(k + 1) / (float)EMBED) * (1.0f - 2.0f * jf);
}

// ---- Kernel 1: query embedding -> state[BN,128] ----
__global__ void k_query(const int* __restrict__ cq, const float* __restrict__ Bw,
                        float* __restrict__ state) {
    int bn = blockIdx.x;
    int d  = threadIdx.x;
    float acc = 0.f;
    #pragma unroll
    for (int s = 0; s < SQ; ++s) {
        int tok = cq[bn * SQ + s];
        acc += Bw[tok * EMBED + d] * posw(s, SQ, d);
    }
    state[bn * EMBED + d] = acc;
}

// ---- Kernel 2: story embeddings -> memb/outb [16,50,128] (hop/query invariant) ----
__global__ void k_story(const int* __restrict__ story, const float* __restrict__ Aw,
                        const float* __restrict__ Cw, const float* __restrict__ TA,
                        const float* __restrict__ TC,
                        float* __restrict__ memb, float* __restrict__ outb) {
    int br = blockIdx.x;          // b*50 + r
    int r  = br % MEMN;
    int d  = threadIdx.x;
    float ma = TA[r * EMBED + d];
    float mc = TC[r * EMBED + d];
    const int* toks = story + br * SS;
    #pragma unroll 4
    for (int s = 0; s < SS; ++s) {
        int tok = toks[s];
        float w = posw(s, SS, d);
        ma += Aw[tok * EMBED + d] * w;
        mc += Cw[tok * EMBED + d] * w;
    }
    memb[br * EMBED + d] = ma;
    outb[br * EMBED + d] = mc;
}

// ---- Kernel 3: transpose H_w so state update reads coalesced ----
__global__ void k_ht(const float* __restrict__ Hw, float* __restrict__ HwT) {
    int k = blockIdx.x, d = threadIdx.x;
    HwT[k * EMBED + d] = Hw[d * EMBED + k];
}

// ---- Kernel 4: 3 hops, one block per query ----
__global__ void k_hops(const float* __restrict__ memb, const float* __restrict__ outb,
                       const float* __restrict__ HwT, const float* __restrict__ Hb,
                       float* __restrict__ state) {
    __shared__ float lmem[MEMN][EMBED + 1];   // +1 pad: logits read row-per-lane
    __shared__ float lout[MEMN][EMBED + 1];
    __shared__ float lstate[EMBED];
    __shared__ float lprobs[MEMN];
    __shared__ float lresp[EMBED];
    int bn = blockIdx.x;
    int b  = bn / NQ;
    int t  = threadIdx.x;   // 128 threads
    for (int i = t; i < MEMN * EMBED; i += EMBED) {
        int r = i >> 7, d = i & 127;
        lmem[r][d] = memb[b * MEMN * EMBED + i];
        lout[r][d] = outb[b * MEMN * EMBED + i];
    }
    lstate[t] = state[bn * EMBED + t];
    __syncthreads();

    for (int hop = 0; hop < NHOPS; ++hop) {
        // logits: thread r (<50) dots mem row with state
        float logit = -1e30f;
        if (t < MEMN) {
            float acc = 0.f;
            for (int d = 0; d < EMBED; ++d) acc += lmem[t][d] * lstate[d];
            logit = acc;
        }
        // softmax entirely inside wave 0 (50 < 64 lanes)
        if (t < 64) {
            float m = logit;
            #pragma unroll
            for (int off = 32; off; off >>= 1) m = fmaxf(m, __shfl_xor(m, off, 64));
            float e = (t < MEMN) ? __expf(logit - m) : 0.f;
            float ssum = e;
            #pragma unroll
            for (int off = 32; off; off >>= 1) ssum += __shfl_xor(ssum, off, 64);
            if (t < MEMN) lprobs[t] = e / ssum;
        }
        __syncthreads();
        // response[d] = sum_r probs[r] * outm[r][d]
        float resp = 0.f;
        for (int r = 0; r < MEMN; ++r) resp += lprobs[r] * lout[r][t];
        lresp[t] = resp;
        __syncthreads();
        // state[d] = Hb[d] + state[d] + sum_k resp[k]*H_w[d,k]  (HwT coalesced)
        float acc = Hb[t] + lstate[t];
        for (int k = 0; k < EMBED; ++k) acc += lresp[k] * HwT[k * EMBED + t];
        __syncthreads();
        lstate[t] = acc;
        __syncthreads();
    }
    state[bn * EMBED + t] = lstate[t];
}

// ---- Kernel 5: out[bn,v] = dot(state[bn], out_w[v])  (160 x 32000 x 128) ----
#define VT  4
#define BNT 8
__global__ void k_out(const float* __restrict__ state, const float* __restrict__ outw,
                      float* __restrict__ out) {
    __shared__ __align__(16) float ls[BNT][EMBED];
    int t   = threadIdx.x;               // 256
    int bn0 = blockIdx.y * BNT;
    for (int i = t; i < BNT * EMBED; i += 256) ls[i >> 7][i & 127] = state[bn0 * EMBED + i];
    __syncthreads();
    int v0 = blockIdx.x * (256 * VT) + t * VT;
    if (v0 >= VOCAB) return;
    float acc[VT][BNT];
    #pragma unroll
    for (int i = 0; i < VT; ++i)
        #pragma unroll
        for (int j = 0; j < BNT; ++j) acc[i][j] = 0.f;

    const float4* w4p = (const float4*)outw;
    const float4* s4p = (const float4*)(&ls[0][0]);
    #pragma unroll 4
    for (int k4 = 0; k4 < EMBED / 4; ++k4) {
        float4 w[VT];
        #pragma unroll
        for (int i = 0; i < VT; ++i) w[i] = w4p[(v0 + i) * (EMBED / 4) + k4];
        #pragma unroll
        for (int j = 0; j < BNT; ++j) {
            float4 s = s4p[j * (EMBED / 4) + k4];   // wave-broadcast LDS read
            #pragma unroll
            for (int i = 0; i < VT; ++i)
                acc[i][j] += w[i].x * s.x + w[i].y * s.y + w[i].z * s.z + w[i].w * s.w;
        }
    }
    #pragma unroll
    for (int j = 0; j < BNT; ++j) {
        float4 o;
        #pragma unroll
        for (int i = 0; i < VT; ++i) ((float*)&o)[i] = acc[i][j];
        *(float4*)(&out[(size_t)(bn0 + j) * VOCAB + v0]) = o;
    }
}

extern "C" void kernel_launch(void* const* d_in, const int* in_sizes, int n_in,
                              void* d_out, int out_size, void* d_ws, size_t ws_size,
                              hipStream_t stream) {
    const int*   ctx_query = (const int*)  d_in[0];
    const int*   story     = (const int*)  d_in[1];
    const float* A_w       = (const float*)d_in[2];
    const float* C_w       = (const float*)d_in[3];
    const float* B_w       = (const float*)d_in[4];
    const float* H_w       = (const float*)d_in[5];
    const float* H_b       = (const float*)d_in[6];
    const float* out_w     = (const float*)d_in[7];
    const float* TA        = (const float*)d_in[8];
    const float* TC        = (const float*)d_in[9];
    float* out = (float*)d_out;

    float* ws    = (float*)d_ws;
    float* state = ws;                                   // 160*128
    float* memb  = state + BN * EMBED;                   // 16*50*128
    float* outb  = memb + BATCH * MEMN * EMBED;          // 16*50*128
    float* HwT   = outb + BATCH * MEMN * EMBED;          // 128*128

    k_query<<<BN, EMBED, 0, stream>>>(ctx_query, B_w, state);
    k_story<<<BATCH * MEMN, EMBED, 0, stream>>>(story, A_w, C_w, TA, TC, memb, outb);
    k_ht<<<EMBED, EMBED, 0, stream>>>(H_w, HwT);
    k_hops<<<BN, EMBED, 0, stream>>>(memb, outb, HwT, H_b, state);
    dim3 g(VOCAB / (256 * VT) + ((VOCAB % (256 * VT)) ? 1 : 0), BN / BNT);
    k_out<<<g, 256, 0, stream>>>(state, out_w, out);
}

// Round 2
// 35.394 us; speedup vs baseline: 2.4325x; 2.4325x over previous
//
#include <hip/hip_runtime.h>
#include <hip/hip_bf16.h>
#include <math.h>

#define EMBED 128
#define VOCAB 32000
#define MEMN  50
#define BATCH 16
#define NQ    10
#define SQ    20
#define SS    40
#define BN    (BATCH*NQ)   // 160
#define NHOPS 3
#define NV    64           // vocab rows per k_out block

typedef short v8s __attribute__((ext_vector_type(8)));
typedef float v4f __attribute__((ext_vector_type(4)));

__device__ __forceinline__ float posw(int j, int J, int k) {
    float jf = (float)(j + 1) / (float)J;
    return 1.0f - jf - ((float)(k + 1) / (float)EMBED) * (1.0f - 2.0f * jf);
}

__device__ __forceinline__ short f2bf(float f) {
    __hip_bfloat16 h = __float2bfloat16(f);
    return *(short*)&h;
}

// ---- Kernel 1 (fused): query embed | story embed | H_w transpose ----
__global__ void k_embed(const int* __restrict__ cq, const int* __restrict__ story,
                        const float* __restrict__ Bw, const float* __restrict__ Aw,
                        const float* __restrict__ Cw, const float* __restrict__ TA,
                        const float* __restrict__ TC, const float* __restrict__ Hw,
                        float* __restrict__ state, float* __restrict__ memb,
                        float* __restrict__ outb, float* __restrict__ HwT) {
    int blk = blockIdx.x;
    int t = threadIdx.x;   // 128
    if (blk < BN) {
        float acc = 0.f;
        #pragma unroll
        for (int s = 0; s < SQ; ++s) {
            int tok = cq[blk * SQ + s];
            acc += Bw[tok * EMBED + t] * posw(s, SQ, t);
        }
        state[blk * EMBED + t] = acc;
    } else if (blk < BN + BATCH * MEMN) {
        int br = blk - BN;
        int r = br % MEMN;
        float ma = TA[r * EMBED + t];
        float mc = TC[r * EMBED + t];
        const int* toks = story + br * SS;
        #pragma unroll 4
        for (int s = 0; s < SS; ++s) {
            int tok = toks[s];
            float w = posw(s, SS, t);
            ma += Aw[tok * EMBED + t] * w;
            mc += Cw[tok * EMBED + t] * w;
        }
        memb[br * EMBED + t] = ma;
        outb[br * EMBED + t] = mc;
    } else {
        int k = blk - (BN + BATCH * MEMN);
        HwT[k * EMBED + t] = Hw[t * EMBED + k];
    }
}

// ---- Kernel 2: 3 hops, one block per query; outputs state as bf16 ----
__global__ void k_hops(const float* __restrict__ memb, const float* __restrict__ outb,
                       const float* __restrict__ HwT, const float* __restrict__ Hb,
                       const float* __restrict__ state, __hip_bfloat16* __restrict__ stateb) {
    __shared__ float lmem[MEMN][EMBED + 1];
    __shared__ float lout[MEMN][EMBED + 1];
    __shared__ float lstate[EMBED];
    __shared__ float lprobs[MEMN];
    __shared__ float lresp[EMBED];
    int bn = blockIdx.x;
    int b  = bn / NQ;
    int t  = threadIdx.x;   // 128
    for (int i = t; i < MEMN * EMBED; i += EMBED) {
        int r = i >> 7, d = i & 127;
        lmem[r][d] = memb[b * MEMN * EMBED + i];
        lout[r][d] = outb[b * MEMN * EMBED + i];
    }
    lstate[t] = state[bn * EMBED + t];
    __syncthreads();

    for (int hop = 0; hop < NHOPS; ++hop) {
        float logit = -1e30f;
        if (t < MEMN) {
            float acc = 0.f;
            for (int d = 0; d < EMBED; ++d) acc += lmem[t][d] * lstate[d];
            logit = acc;
        }
        if (t < 64) {
            float m = logit;
            #pragma unroll
            for (int off = 32; off; off >>= 1) m = fmaxf(m, __shfl_xor(m, off, 64));
            float e = (t < MEMN) ? __expf(logit - m) : 0.f;
            float ssum = e;
            #pragma unroll
            for (int off = 32; off; off >>= 1) ssum += __shfl_xor(ssum, off, 64);
            if (t < MEMN) lprobs[t] = e / ssum;
        }
        __syncthreads();
        float resp = 0.f;
        for (int r = 0; r < MEMN; ++r) resp += lprobs[r] * lout[r][t];
        lresp[t] = resp;
        __syncthreads();
        float acc = Hb[t] + lstate[t];
        for (int k = 0; k < EMBED; ++k) acc += lresp[k] * HwT[k * EMBED + t];
        __syncthreads();
        lstate[t] = acc;
        __syncthreads();
    }
    stateb[bn * EMBED + t] = __float2bfloat16(lstate[t]);
}

// ---- Kernel 3: out[160,32000] = state_bf16 @ W^T via MFMA 16x16x32 ----
// Block: 256 thr (4 waves). Tile: all 160 bn x 64 vocab. A,B staged in LDS (bf16).
__global__ __launch_bounds__(256) void k_out(const __hip_bfloat16* __restrict__ stateb,
                                             const float* __restrict__ outw,
                                             float* __restrict__ out) {
    __shared__ __align__(16) __hip_bfloat16 Alds[BN][EMBED + 8];   // 160 x 136
    __shared__ __align__(16) __hip_bfloat16 Blds[NV][EMBED + 8];   // 64 x 136
    int t = threadIdx.x;
    int vbase = blockIdx.x * NV;

    // Stage A: 160*128 bf16 = 2560 16B-chunks, coalesced
    #pragma unroll
    for (int i = 0; i < 10; ++i) {
        int e = t + i * 256;           // 0..2559
        int row = e >> 4, c8 = (e & 15) << 3;
        *(int4*)&Alds[row][c8] = *(const int4*)&stateb[row * EMBED + c8];
    }
    // Stage B: 64 rows x 128 f32, convert to bf16. 2048 float4 chunks.
    #pragma unroll
    for (int i = 0; i < 8; ++i) {
        int e = t + i * 256;           // 0..2047
        int row = e >> 5, c4 = (e & 31) << 2;
        float4 w = *(const float4*)&outw[(size_t)(vbase + row) * EMBED + c4];
        short4 p;
        p.x = f2bf(w.x); p.y = f2bf(w.y); p.z = f2bf(w.z); p.w = f2bf(w.w);
        *(short4*)&Blds[row][c4] = p;
    }
    __syncthreads();

    int wv = t >> 6;                  // wave id: N-tile
    int l = t & 63;
    int col16 = l & 15;
    int kg = l >> 4;                  // k-group 0..3

    v8s bfrag[4];
    #pragma unroll
    for (int k4 = 0; k4 < 4; ++k4)
        bfrag[k4] = *(v8s*)&Blds[(wv << 4) + col16][k4 * 32 + kg * 8];

    v4f acc[10];
    #pragma unroll
    for (int m = 0; m < 10; ++m) acc[m] = (v4f){0.f, 0.f, 0.f, 0.f};

    #pragma unroll
    for (int k4 = 0; k4 < 4; ++k4) {
        #pragma unroll
        for (int m = 0; m < 10; ++m) {
            v8s af = *(v8s*)&Alds[m * 16 + col16][k4 * 32 + kg * 8];
            acc[m] = __builtin_amdgcn_mfma_f32_16x16x32_bf16(af, bfrag[k4], acc[m], 0, 0, 0);
        }
    }

    int colg = vbase + (wv << 4) + col16;
    #pragma unroll
    for (int m = 0; m < 10; ++m) {
        #pragma unroll
        for (int i = 0; i < 4; ++i) {
            out[(size_t)(m * 16 + kg * 4 + i) * VOCAB + colg] = acc[m][i];
        }
    }
}

extern "C" void kernel_launch(void* const* d_in, const int* in_sizes, int n_in,
                              void* d_out, int out_size, void* d_ws, size_t ws_size,
                              hipStream_t stream) {
    const int*   ctx_query = (const int*)  d_in[0];
    const int*   story     = (const int*)  d_in[1];
    const float* A_w       = (const float*)d_in[2];
    const float* C_w       = (const float*)d_in[3];
    const float* B_w       = (const float*)d_in[4];
    const float* H_w       = (const float*)d_in[5];
    const float* H_b       = (const float*)d_in[6];
    const float* out_w     = (const float*)d_in[7];
    const float* TA        = (const float*)d_in[8];
    const float* TC        = (const float*)d_in[9];
    float* out = (float*)d_out;

    float* ws    = (float*)d_ws;
    float* state = ws;                                   // 160*128 f32
    float* memb  = state + BN * EMBED;                   // 16*50*128
    float* outb  = memb + BATCH * MEMN * EMBED;          // 16*50*128
    float* HwT   = outb + BATCH * MEMN * EMBED;          // 128*128
    __hip_bfloat16* stateb = (__hip_bfloat16*)(HwT + EMBED * EMBED);  // 160*128 bf16

    k_embed<<<BN + BATCH * MEMN + EMBED, EMBED, 0, stream>>>(
        ctx_query, story, B_w, A_w, C_w, TA, TC, H_w, state, memb, outb, HwT);
    k_hops<<<BN, EMBED, 0, stream>>>(memb, outb, HwT, H_b, state, stateb);
    k_out<<<VOCAB / NV, 256, 0, stream>>>(stateb, out_w, out);
}